// Round 1
// baseline (421.791 us; speedup 1.0000x reference)
//
#include <hip/hip_runtime.h>
#include <hip/hip_fp16.h>

#define N_NODES 100000
#define N_EDGES 1600000
#define N_GRAPHS 512
#define F_IN 20
#define HID 128
#define OUT_F 64

#define BUCKETS 512
#define SPAN 196        // ceil(N_NODES / BUCKETS)
#define BCAP 3500       // per-bucket capacity (mean 3125, +6.7 sigma)
#define EPB 4096        // edges per partition block (512 threads x 8)

typedef _Float16 half8_t __attribute__((ext_vector_type(8)));
typedef float f32x4_t __attribute__((ext_vector_type(4)));

__device__ inline float4 h4_to_f4(uint2 u) {
    __half2 h0 = *(__half2*)&u.x;
    __half2 h1 = *(__half2*)&u.y;
    float2 f0 = __half22float2(h0);
    float2 f1 = __half22float2(h1);
    return make_float4(f0.x, f0.y, f1.x, f1.y);
}

// ---------------- partition edges into 512 dst-range buckets (512 thr) ----------------
__global__ __launch_bounds__(512) void partition(const int* __restrict__ src,
                                                 const int* __restrict__ dst,
                                                 int* __restrict__ bpairs,
                                                 int* cur512) {
    __shared__ int lcnt[8][BUCKETS];   // 16 KB
    __shared__ int woff[8][BUCKETS];   // 16 KB
    int t = threadIdx.x;
    int wv = t >> 6;
    for (int i = t; i < 8 * BUCKETS; i += 512) ((int*)lcnt)[i] = 0;
    __syncthreads();
    int base = blockIdx.x * EPB;
    int myb[8], myp[8], myr[8];
#pragma unroll
    for (int i = 0; i < 8; ++i) {
        int e = base + i * 512 + t;
        int b = -1, p = 0, rk = 0;
        if (e < N_EDGES) {
            int s = src[e], d = dst[e];
            b = d / SPAN;
            p = (s << 9) | (d - b * SPAN);
            rk = atomicAdd(&lcnt[wv][b], 1);
        }
        myb[i] = b; myp[i] = p; myr[i] = rk;
    }
    __syncthreads();
    {
        int c[8], tot = 0;
#pragma unroll
        for (int w = 0; w < 8; ++w) { c[w] = lcnt[w][t]; tot += c[w]; }
        int gb = atomicAdd(&cur512[t], tot);
#pragma unroll
        for (int w = 0; w < 8; ++w) { woff[w][t] = gb; gb += c[w]; }
    }
    __syncthreads();
#pragma unroll
    for (int i = 0; i < 8; ++i) {
        int b = myb[i];
        if (b >= 0) {
            int p = woff[wv][b] + myr[i];
            if (p < BCAP) bpairs[(size_t)b * BCAP + p] = myp[i];
        }
    }
}

// ---------------- per-bucket CSR build, 512 thr (fused bbase scan + scale_x) ----------------
__global__ __launch_bounds__(512) void csr_build(const int* __restrict__ bpairs,
                                                 const int* __restrict__ cur512,
                                                 int* __restrict__ row_st,
                                                 int* __restrict__ csr,
                                                 const float* __restrict__ x,
                                                 __half* __restrict__ Xs) {
    __shared__ int ocnt[SPAN];
    __shared__ int sc[512];
    __shared__ int cur[SPAN];
    __shared__ int sbase;
    int b = blockIdx.x, t = threadIdx.x;

    // bucket base: exclusive scan of all 512 bucket counts
    int myc = cur512[t];
    sc[t] = myc;
    __syncthreads();
    for (int o = 1; o < BUCKETS; o <<= 1) {
        int v = (t >= o) ? sc[t - o] : 0;
        __syncthreads();
        sc[t] += v;
        __syncthreads();
    }
    if (t == b) sbase = sc[t] - myc;
    if (b == BUCKETS - 1 && t == 0) row_st[N_NODES] = N_EDGES;

    int n0 = b * SPAN;
    int span = N_NODES - n0; if (span > SPAN) span = SPAN;
    if (span < 0) span = 0;
    if (t < SPAN) ocnt[t] = 0;
    __syncthreads();

    int n = cur512[b];
    if (n > BCAP) n = BCAP;
    const int* p = bpairs + (size_t)b * BCAP;
    for (int i = t; i < n; i += 512) atomicAdd(&ocnt[p[i] & 511], 1);
    __syncthreads();
    sc[t] = (t < span) ? ocnt[t] : 0;
    __syncthreads();
    for (int o = 1; o < 512; o <<= 1) {
        int v = (t >= o) ? sc[t - o] : 0;
        __syncthreads();
        sc[t] += v;
        __syncthreads();
    }
    int base = sbase;
    if (t < span) {
        int start = sc[t] - ocnt[t];
        row_st[n0 + t] = base + start;
        cur[t] = start;
    }
    __syncthreads();
    for (int i = t; i < n; i += 512) {
        int e = p[i];
        int lp = atomicAdd(&cur[e & 511], 1);
        csr[base + lp] = e >> 9;
    }
    // fused scale_x for this bucket's nodes
    for (int i = t; i < span * 32; i += 512) {
        int nl = i >> 5, f = i & 31;
        float v = (f < F_IN) ? x[(size_t)(n0 + nl) * F_IN + f] : 0.f;
        float di = rsqrtf((float)(ocnt[nl] + 1));
        Xs[(size_t)(n0 + nl) * 32 + f] = __float2half(di * v);
    }
}

// ---------------- layer 1 fused: gather(F_IN) + GEMM -> H fp16 (slice-major out) ----------------
__global__ __launch_bounds__(256) void layer1(const __half* __restrict__ Xs,
                                              const int* __restrict__ row_st,
                                              const int* __restrict__ csr,
                                              const float* __restrict__ W,
                                              const float* __restrict__ bias,
                                              __half* __restrict__ H) {
    __shared__ float Wlds[F_IN * HID];   // 10 KB
    __shared__ float Alds[16 * F_IN];
    const int t = threadIdx.x;
    const int node0 = blockIdx.x * 16;

    for (int i = t; i < F_IN * HID; i += 256) Wlds[i] = W[i];

    const int h16 = t >> 4;          // 0..15 -> local node
    const int l16 = t & 15;          // feature pair
    const __half2* X2 = (const __half2*)Xs;   // 16 half2 per row
    {
        int nn = node0 + h16;
        int r0 = row_st[nn], r1 = row_st[nn + 1];
        float2 f = __half22float2(X2[(size_t)nn * 16 + l16]);
        float2 acc = f;   // self term
        int r = r0;
        for (; r + 1 < r1; r += 2) {
            float2 f0 = __half22float2(X2[(size_t)csr[r] * 16 + l16]);
            float2 f1 = __half22float2(X2[(size_t)csr[r + 1] * 16 + l16]);
            acc.x += f0.x + f1.x;
            acc.y += f0.y + f1.y;
        }
        if (r < r1) {
            float2 f2 = __half22float2(X2[(size_t)csr[r] * 16 + l16]);
            acc.x += f2.x; acc.y += f2.y;
        }
        if (l16 < 10) {
            float di = rsqrtf((float)(r1 - r0 + 1));
            Alds[h16 * F_IN + l16 * 2]     = di * acc.x;
            Alds[h16 * F_IN + l16 * 2 + 1] = di * acc.y;
        }
    }
    __syncthreads();

    // GEMM phase
    const int g  = t >> 5;
    const int h4 = (t & 31) * 4;
    float4 b4 = *(const float4*)&bias[h4];
    float4 acc0 = b4;
    float4 acc1 = b4;
#pragma unroll
    for (int kk = 0; kk < F_IN; ++kk) {
        float a0 = Alds[(g * 2) * F_IN + kk];
        float a1 = Alds[(g * 2 + 1) * F_IN + kk];
        float4 w = *(const float4*)&Wlds[kk * HID + h4];
        acc0.x = fmaf(a0, w.x, acc0.x);
        acc0.y = fmaf(a0, w.y, acc0.y);
        acc0.z = fmaf(a0, w.z, acc0.z);
        acc0.w = fmaf(a0, w.w, acc0.w);
        acc1.x = fmaf(a1, w.x, acc1.x);
        acc1.y = fmaf(a1, w.y, acc1.y);
        acc1.z = fmaf(a1, w.z, acc1.z);
        ac1:
        acc1.w = fmaf(a1, w.w, acc1.w);
    }
    // slice-major store: slice = h4>>5 (32 features per slice), uint2 idx within slice row
    const size_t sl = (size_t)(h4 >> 5) * N_NODES;
    const int wi = (h4 >> 2) & 7;
    {
        __half2 h0 = __floats2half2_rn(acc0.x, acc0.y);
        __half2 h1 = __floats2half2_rn(acc0.z, acc0.w);
        uint2 u; u.x = *(unsigned*)&h0; u.y = *(unsigned*)&h1;
        ((uint2*)H)[(sl + node0 + g * 2) * 8 + wi] = u;
    }
    {
        __half2 h0 = __floats2half2_rn(acc1.x, acc1.y);
        __half2 h1 = __floats2half2_rn(acc1.z, acc1.w);
        uint2 u; u.x = *(unsigned*)&h0; u.y = *(unsigned*)&h1;
        ((uint2*)H)[(sl + node0 + g * 2 + 1) * 8 + wi] = u;
    }
}

// ---------------- layers-2/3 GEMM via MFMA (column-split: 64 cols/block) ----------------
// A is read slice-major (slice = kc); T written slice-major.
__global__ __launch_bounds__(256) void gemm_mfma(const __half* __restrict__ H,
                                                 const float* __restrict__ W,
                                                 const int* __restrict__ row_st,
                                                 __half* __restrict__ T) {
    __shared__ _Float16 Whi[64 * 128];   // 16 KB
    __shared__ _Float16 Wlo[64 * 128];   // 16 KB
    const int t = threadIdx.x;
    const int c0 = (blockIdx.x & 1) * 64;

    for (int i = t; i < 128 * 64; i += 256) {
        int k = i >> 6, c = i & 63;
        float w = W[k * HID + c0 + c];
        _Float16 hi = (_Float16)w;
        _Float16 lo = (_Float16)((w - (float)hi) * 2048.0f);
        int addr = c * 128 + (((k >> 3) ^ (c & 15)) << 3) + (k & 7);
        Whi[addr] = hi;
        Wlo[addr] = lo;
    }
    __syncthreads();

    const int wv = t >> 6;
    const int l  = t & 63;
    const int lr = l & 15;
    const int lq = l >> 4;

    for (int rep = 0; rep < 4; ++rep) {
        int strip = ((blockIdx.x >> 1) * 4 + wv) * 4 + rep;
        if (strip >= N_NODES / 16) continue;
        int n0 = strip * 16;

        f32x4_t acc[4], acl[4];
#pragma unroll
        for (int ct = 0; ct < 4; ++ct) { acc[ct] = (f32x4_t){0,0,0,0}; acl[ct] = (f32x4_t){0,0,0,0}; }

#pragma unroll
        for (int kc = 0; kc < 4; ++kc) {
            // slice kc, 32 halfs per node-row
            half8_t a = *(const half8_t*)(H + ((size_t)kc * N_NODES + n0 + lr) * 32 + lq * 8);
#pragma unroll
            for (int j = 0; j < 8; ++j) a[j] = a[j] > (_Float16)0 ? a[j] : (_Float16)0;
            int g = kc * 4 + lq;
#pragma unroll
            for (int ct = 0; ct < 4; ++ct) {
                int c = ct * 16 + lr;
                int addr = c * 128 + ((g ^ lr) << 3);
                half8_t bh = *(const half8_t*)&Whi[addr];
                half8_t bl = *(const half8_t*)&Wlo[addr];
                acc[ct] = __builtin_amdgcn_mfma_f32_16x16x32_f16(a, bh, acc[ct], 0, 0, 0);
                acl[ct] = __builtin_amdgcn_mfma_f32_16x16x32_f16(a, bl, acl[ct], 0, 0, 0);
            }
        }

        int r0 = n0 + lq * 4;
#pragma unroll
        for (int r = 0; r < 4; ++r) {
            int row = r0 + r;
            float d = rsqrtf((float)(row_st[row + 1] - row_st[row] + 1));
#pragma unroll
            for (int ct = 0; ct < 4; ++ct) {
                float v = (acc[ct][r] + acl[ct][r] * 4.8828125e-4f) * d;
                int c = c0 + ct * 16 + lr;
                T[((size_t)(c >> 5) * N_NODES + row) * 32 + (c & 31)] = __float2half(v);
            }
        }
    }
}

// ---------------- XCD-pinned sliced gather: 4 slices x 32 features ----------------
// blockIdx%8 -> XCD (round-robin dispatch); 2 XCDs per slice => per-XCD working set
// = one 6.4 MB slice table, mostly L2-resident. 8-lane groups, 64-B requests.
// csr reads + output stores are non-temporal to avoid evicting the slice table.
__global__ __launch_bounds__(256) void gather_slice(const __half* __restrict__ T,
                                                    const int* __restrict__ row_st,
                                                    const int* __restrict__ csr,
                                                    const float* __restrict__ bias,
                                                    __half* __restrict__ B) {
    int t = threadIdx.x;
    int b = blockIdx.x;
    int x = b & 7;
    int slice = x >> 1;                      // 2 XCDs per slice
    int chunk = (b >> 3) * 2 + (x & 1);      // dst chunk within slice
    int grp = t >> 3;                        // 32 groups of 8 lanes
    int l   = t & 7;
    int n = chunk * 32 + grp;
    if (n >= N_NODES) return;
    int r0 = row_st[n], r1 = row_st[n + 1];
    float di = rsqrtf((float)(r1 - r0 + 1));
    const uint2* Tf = (const uint2*)T + (size_t)slice * N_NODES * 8;
    float4 acc = h4_to_f4(Tf[(size_t)n * 8 + l]);   // self term
    int r = r0;
    for (; r + 7 < r1; r += 8) {
        int s0 = __builtin_nontemporal_load(csr + r);
        int s1 = __builtin_nontemporal_load(csr + r + 1);
        int s2 = __builtin_nontemporal_load(csr + r + 2);
        int s3 = __builtin_nontemporal_load(csr + r + 3);
        int s4 = __builtin_nontemporal_load(csr + r + 4);
        int s5 = __builtin_nontemporal_load(csr + r + 5);
        int s6 = __builtin_nontemporal_load(csr + r + 6);
        int s7 = __builtin_nontemporal_load(csr + r + 7);
        float4 v0 = h4_to_f4(Tf[(size_t)s0 * 8 + l]);
        float4 v1 = h4_to_f4(Tf[(size_t)s1 * 8 + l]);
        float4 v2 = h4_to_f4(Tf[(size_t)s2 * 8 + l]);
        float4 v3 = h4_to_f4(Tf[(size_t)s3 * 8 + l]);
        float4 v4 = h4_to_f4(Tf[(size_t)s4 * 8 + l]);
        float4 v5 = h4_to_f4(Tf[(size_t)s5 * 8 + l]);
        float4 v6 = h4_to_f4(Tf[(size_t)s6 * 8 + l]);
        float4 v7 = h4_to_f4(Tf[(size_t)s7 * 8 + l]);
        acc.x += ((v0.x + v1.x) + (v2.x + v3.x)) + ((v4.x + v5.x) + (v6.x + v7.x));
        acc.y += ((v0.y + v1.y) + (v2.y + v3.y)) + ((v4.y + v5.y) + (v6.y + v7.y));
        acc.z += ((v0.z + v1.z) + (v2.z + v3.z)) + ((v4.z + v5.z) + (v6.z + v7.z));
        acc.w += ((v0.w + v1.w) + (v2.w + v3.w)) + ((v4.w + v5.w) + (v6.w + v7.w));
    }
    for (; r + 3 < r1; r += 4) {
        int s0 = __builtin_nontemporal_load(csr + r);
        int s1 = __builtin_nontemporal_load(csr + r + 1);
        int s2 = __builtin_nontemporal_load(csr + r + 2);
        int s3 = __builtin_nontemporal_load(csr + r + 3);
        float4 v0 = h4_to_f4(Tf[(size_t)s0 * 8 + l]);
        float4 v1 = h4_to_f4(Tf[(size_t)s1 * 8 + l]);
        float4 v2 = h4_to_f4(Tf[(size_t)s2 * 8 + l]);
        float4 v3 = h4_to_f4(Tf[(size_t)s3 * 8 + l]);
        acc.x += (v0.x + v1.x) + (v2.x + v3.x);
        acc.y += (v0.y + v1.y) + (v2.y + v3.y);
        acc.z += (v0.z + v1.z) + (v2.z + v3.z);
        acc.w += (v0.w + v1.w) + (v2.w + v3.w);
    }
    for (; r < r1; ++r) {
        int s0 = __builtin_nontemporal_load(csr + r);
        float4 v = h4_to_f4(Tf[(size_t)s0 * 8 + l]);
        acc.x += v.x; acc.y += v.y; acc.z += v.z; acc.w += v.w;
    }
    float4 b4 = ((const float4*)bias)[slice * 8 + l];
    __half2 h0 = __floats2half2_rn(fmaf(di, acc.x, b4.x), fmaf(di, acc.y, b4.y));
    __half2 h1 = __floats2half2_rn(fmaf(di, acc.z, b4.z), fmaf(di, acc.w, b4.w));
    unsigned lo = *(unsigned*)&h0, hi = *(unsigned*)&h1;
    unsigned long long uv = ((unsigned long long)hi << 32) | lo;
    unsigned long long* dst = (unsigned long long*)((uint2*)B + ((size_t)slice * N_NODES + n) * 8 + l);
    __builtin_nontemporal_store(uv, dst);
}

// ---------------- pool + head in one kernel, no atomics (batch is sorted) ----------------
__global__ __launch_bounds__(256) void pool_head(const __half* __restrict__ H,
                                                 const int* __restrict__ batch,
                                                 const float* __restrict__ Wout,
                                                 const float* __restrict__ bout,
                                                 float* __restrict__ out) {
    __shared__ float4 part[8][32];
    __shared__ float p[HID];
    __shared__ int bounds[2];
    int g = blockIdx.x;
    int t = threadIdx.x;
    if (t < 2) {
        int target = g + t;
        int lo = 0, hi = N_NODES;
        while (lo < hi) {
            int mid = (lo + hi) >> 1;
            if (batch[mid] < target) lo = mid + 1; else hi = mid;
        }
        bounds[t] = lo;
    }
    __syncthreads();
    int lo = bounds[0], hi = bounds[1];
    int grp = t >> 5, l = t & 31;
    const uint2* Hf = (const uint2*)H;
    float4 acc = make_float4(0.f, 0.f, 0.f, 0.f);
    // slice-major read: feature quad l -> slice l>>3, within-slice uint2 idx l&7
    const size_t sbase = (size_t)(l >> 3) * N_NODES;
    const int wi = l & 7;
    for (int n = lo + grp; n < hi; n += 8) {
        float4 v = h4_to_f4(Hf[(sbase + n) * 8 + wi]);
        acc.x += fmaxf(v.x, 0.f);
        acc.y += fmaxf(v.y, 0.f);
        acc.z += fmaxf(v.z, 0.f);
        acc.w += fmaxf(v.w, 0.f);
    }
    part[grp][l] = acc;
    __syncthreads();
    if (t < 32) {
        float4 s = part[0][t];
#pragma unroll
        for (int j = 1; j < 8; ++j) {
            float4 v = part[j][t];
            s.x += v.x; s.y += v.y; s.z += v.z; s.w += v.w;
        }
        float inv = 1.0f / fmaxf((float)(hi - lo), 1.0f);
        p[t * 4 + 0] = s.x * inv;
        p[t * 4 + 1] = s.y * inv;
        p[t * 4 + 2] = s.z * inv;
        p[t * 4 + 3] = s.w * inv;
    }
    __syncthreads();
    if (t < OUT_F) {
        float acc2 = 0.f;
#pragma unroll 8
        for (int k = 0; k < HID; ++k)
            acc2 = fmaf(p[k], Wout[k * OUT_F + t], acc2);
        out[g * OUT_F + t] = acc2 + bout[t];
    }
}

extern "C" void kernel_launch(void* const* d_in, const int* in_sizes, int n_in,
                              void* d_out, int out_size, void* d_ws, size_t ws_size,
                              hipStream_t stream) {
    const float* x     = (const float*)d_in[0];
    const int*   ei    = (const int*)d_in[1];
    const int*   batch = (const int*)d_in[2];
    const float* W1    = (const float*)d_in[3];
    const float* b1    = (const float*)d_in[4];
    const float* W2    = (const float*)d_in[5];
    const float* b2    = (const float*)d_in[6];
    const float* W3    = (const float*)d_in[7];
    const float* b3    = (const float*)d_in[8];
    const float* Wout  = (const float*)d_in[9];
    const float* bout  = (const float*)d_in[10];
    float* out = (float*)d_out;

    const int* src = ei;
    const int* dst = ei + N_EDGES;

    // workspace (within proven footprint)
    float* A      = (float*)d_ws;                        // 12.8M floats
    float* Breg   = A + (size_t)N_NODES * HID;           // 12.8M floats
    int*   row_st = (int*)(Breg + (size_t)N_NODES * HID);// 100001 ints
    int*   cur512 = row_st + N_NODES + 1;                // 512
    int*   csr    = cur512 + BUCKETS;                    // 1.6M ints

    int*    bpairs = (int*)A;                              // 512*3500*4 = 7.168 MB overlay
    __half* Xs     = (__half*)((char*)A + 7168000);        // 6.4 MB, after bpairs
    __half* T      = (__half*)A;                           // 25.6 MB msg table (after layer1)
    __half* H      = (__half*)Breg;                        // 25.6 MB activation table

    // 1. zero bucket cursors + CSR build
    hipMemsetAsync(cur512, 0, BUCKETS * sizeof(int), stream);
    partition<<<(N_EDGES + EPB - 1) / EPB, 512, 0, stream>>>(src, dst, bpairs, cur512);
    csr_build<<<BUCKETS, 512, 0, stream>>>(bpairs, cur512, row_st, csr, x, Xs);

    // 2. layer 1: fused gather(F_IN)+GEMM (slice-major H)
    layer1<<<N_NODES / 16, 256, 0, stream>>>(Xs, row_st, csr, W1, b1, H);

    // 3. layers 2/3: slice-major tables, XCD-pinned sliced gather
    // gather grid: 1563*8 = 12504 blocks; chunk coverage 0..3125 (>=3125 guarded)
    gemm_mfma<<<782, 256, 0, stream>>>(H, W2, row_st, T);
    gather_slice<<<12504, 256, 0, stream>>>(T, row_st, csr, b2, H);
    gemm_mfma<<<782, 256, 0, stream>>>(H, W3, row_st, T);
    gather_slice<<<12504, 256, 0, stream>>>(T, row_st, csr, b3, H);

    // 4. pool + head, no atomics
    pool_head<<<N_GRAPHS, 256, 0, stream>>>(H, batch, Wout, bout, out);
}

// Round 2
// 362.636 us; speedup vs baseline: 1.1631x; 1.1631x over previous
//
#include <hip/hip_runtime.h>
#include <hip/hip_fp16.h>

#define N_NODES 100000
#define N_EDGES 1600000
#define N_GRAPHS 512
#define F_IN 20
#define HID 128
#define OUT_F 64

#define BUCKETS 512
#define SPAN 196        // ceil(N_NODES / BUCKETS)
#define BCAP 3500       // per-bucket capacity (mean 3125, +6.7 sigma)
#define EPB 4096        // edges per partition block (512 threads x 8)

typedef _Float16 half8_t __attribute__((ext_vector_type(8)));
typedef float f32x4_t __attribute__((ext_vector_type(4)));

__device__ inline float4 h4_to_f4(uint2 u) {
    __half2 h0 = *(__half2*)&u.x;
    __half2 h1 = *(__half2*)&u.y;
    float2 f0 = __half22float2(h0);
    float2 f1 = __half22float2(h1);
    return make_float4(f0.x, f0.y, f1.x, f1.y);
}

// ---------------- partition edges into 512 dst-range buckets (512 thr) ----------------
__global__ __launch_bounds__(512) void partition(const int* __restrict__ src,
                                                 const int* __restrict__ dst,
                                                 int* __restrict__ bpairs,
                                                 int* cur512) {
    __shared__ int lcnt[8][BUCKETS];   // 16 KB
    __shared__ int woff[8][BUCKETS];   // 16 KB
    int t = threadIdx.x;
    int wv = t >> 6;
    for (int i = t; i < 8 * BUCKETS; i += 512) ((int*)lcnt)[i] = 0;
    __syncthreads();
    int base = blockIdx.x * EPB;
    int myb[8], myp[8], myr[8];
#pragma unroll
    for (int i = 0; i < 8; ++i) {
        int e = base + i * 512 + t;
        int b = -1, p = 0, rk = 0;
        if (e < N_EDGES) {
            int s = src[e], d = dst[e];
            b = d / SPAN;
            p = (s << 9) | (d - b * SPAN);
            rk = atomicAdd(&lcnt[wv][b], 1);
        }
        myb[i] = b; myp[i] = p; myr[i] = rk;
    }
    __syncthreads();
    {
        int c[8], tot = 0;
#pragma unroll
        for (int w = 0; w < 8; ++w) { c[w] = lcnt[w][t]; tot += c[w]; }
        int gb = atomicAdd(&cur512[t], tot);
#pragma unroll
        for (int w = 0; w < 8; ++w) { woff[w][t] = gb; gb += c[w]; }
    }
    __syncthreads();
#pragma unroll
    for (int i = 0; i < 8; ++i) {
        int b = myb[i];
        if (b >= 0) {
            int p = woff[wv][b] + myr[i];
            if (p < BCAP) bpairs[(size_t)b * BCAP + p] = myp[i];
        }
    }
}

// ---------------- per-bucket CSR build, 512 thr (fused bbase scan + scale_x) ----------------
__global__ __launch_bounds__(512) void csr_build(const int* __restrict__ bpairs,
                                                 const int* __restrict__ cur512,
                                                 int* __restrict__ row_st,
                                                 int* __restrict__ csr,
                                                 const float* __restrict__ x,
                                                 __half* __restrict__ Xs) {
    __shared__ int ocnt[SPAN];
    __shared__ int sc[512];
    __shared__ int cur[SPAN];
    __shared__ int sbase;
    int b = blockIdx.x, t = threadIdx.x;

    // bucket base: exclusive scan of all 512 bucket counts
    int myc = cur512[t];
    sc[t] = myc;
    __syncthreads();
    for (int o = 1; o < BUCKETS; o <<= 1) {
        int v = (t >= o) ? sc[t - o] : 0;
        __syncthreads();
        sc[t] += v;
        __syncthreads();
    }
    if (t == b) sbase = sc[t] - myc;
    if (b == BUCKETS - 1 && t == 0) row_st[N_NODES] = N_EDGES;

    int n0 = b * SPAN;
    int span = N_NODES - n0; if (span > SPAN) span = SPAN;
    if (span < 0) span = 0;
    if (t < SPAN) ocnt[t] = 0;
    __syncthreads();

    int n = cur512[b];
    if (n > BCAP) n = BCAP;
    const int* p = bpairs + (size_t)b * BCAP;
    for (int i = t; i < n; i += 512) atomicAdd(&ocnt[p[i] & 511], 1);
    __syncthreads();
    sc[t] = (t < span) ? ocnt[t] : 0;
    __syncthreads();
    for (int o = 1; o < 512; o <<= 1) {
        int v = (t >= o) ? sc[t - o] : 0;
        __syncthreads();
        sc[t] += v;
        __syncthreads();
    }
    int base = sbase;
    if (t < span) {
        int start = sc[t] - ocnt[t];
        row_st[n0 + t] = base + start;
        cur[t] = start;
    }
    __syncthreads();
    for (int i = t; i < n; i += 512) {
        int e = p[i];
        int lp = atomicAdd(&cur[e & 511], 1);
        csr[base + lp] = e >> 9;
    }
    // fused scale_x for this bucket's nodes
    for (int i = t; i < span * 32; i += 512) {
        int nl = i >> 5, f = i & 31;
        float v = (f < F_IN) ? x[(size_t)(n0 + nl) * F_IN + f] : 0.f;
        float di = rsqrtf((float)(ocnt[nl] + 1));
        Xs[(size_t)(n0 + nl) * 32 + f] = __float2half(di * v);
    }
}

// ---------------- layer 1 fused: gather(F_IN) + GEMM -> H fp16 (2-slice layout out) ----------------
__global__ __launch_bounds__(256) void layer1(const __half* __restrict__ Xs,
                                              const int* __restrict__ row_st,
                                              const int* __restrict__ csr,
                                              const float* __restrict__ W,
                                              const float* __restrict__ bias,
                                              __half* __restrict__ H) {
    __shared__ float Wlds[F_IN * HID];   // 10 KB
    __shared__ float Alds[16 * F_IN];
    const int t = threadIdx.x;
    const int node0 = blockIdx.x * 16;

    for (int i = t; i < F_IN * HID; i += 256) Wlds[i] = W[i];

    const int h16 = t >> 4;          // 0..15 -> local node
    const int l16 = t & 15;          // feature pair
    const __half2* X2 = (const __half2*)Xs;   // 16 half2 per row
    {
        int nn = node0 + h16;
        int r0 = row_st[nn], r1 = row_st[nn + 1];
        float2 f = __half22float2(X2[(size_t)nn * 16 + l16]);
        float2 acc = f;   // self term
        int r = r0;
        for (; r + 1 < r1; r += 2) {
            float2 f0 = __half22float2(X2[(size_t)csr[r] * 16 + l16]);
            float2 f1 = __half22float2(X2[(size_t)csr[r + 1] * 16 + l16]);
            acc.x += f0.x + f1.x;
            acc.y += f0.y + f1.y;
        }
        if (r < r1) {
            float2 f2 = __half22float2(X2[(size_t)csr[r] * 16 + l16]);
            acc.x += f2.x; acc.y += f2.y;
        }
        if (l16 < 10) {
            float di = rsqrtf((float)(r1 - r0 + 1));
            Alds[h16 * F_IN + l16 * 2]     = di * acc.x;
            Alds[h16 * F_IN + l16 * 2 + 1] = di * acc.y;
        }
    }
    __syncthreads();

    // GEMM phase
    const int g  = t >> 5;
    const int h4 = (t & 31) * 4;
    float4 b4 = *(const float4*)&bias[h4];
    float4 acc0 = b4;
    float4 acc1 = b4;
#pragma unroll
    for (int kk = 0; kk < F_IN; ++kk) {
        float a0 = Alds[(g * 2) * F_IN + kk];
        float a1 = Alds[(g * 2 + 1) * F_IN + kk];
        float4 w = *(const float4*)&Wlds[kk * HID + h4];
        acc0.x = fmaf(a0, w.x, acc0.x);
        acc0.y = fmaf(a0, w.y, acc0.y);
        acc0.z = fmaf(a0, w.z, acc0.z);
        acc0.w = fmaf(a0, w.w, acc0.w);
        acc1.x = fmaf(a1, w.x, acc1.x);
        acc1.y = fmaf(a1, w.y, acc1.y);
        acc1.z = fmaf(a1, w.z, acc1.z);
        acc1.w = fmaf(a1, w.w, acc1.w);
    }
    // 2-slice store: slice = (t&31)>>4 (64 features per slice), uint2 idx = t&15
    const size_t sl = (size_t)((t & 31) >> 4) * N_NODES;
    const int wi = t & 15;
    {
        __half2 h0 = __floats2half2_rn(acc0.x, acc0.y);
        __half2 h1 = __floats2half2_rn(acc0.z, acc0.w);
        uint2 u; u.x = *(unsigned*)&h0; u.y = *(unsigned*)&h1;
        ((uint2*)H)[(sl + node0 + g * 2) * 16 + wi] = u;
    }
    {
        __half2 h0 = __floats2half2_rn(acc1.x, acc1.y);
        __half2 h1 = __floats2half2_rn(acc1.z, acc1.w);
        uint2 u; u.x = *(unsigned*)&h0; u.y = *(unsigned*)&h1;
        ((uint2*)H)[(sl + node0 + g * 2 + 1) * 16 + wi] = u;
    }
}

// ---------------- layers-2/3 GEMM via MFMA (column-split: 64 cols/block) ----------------
// H read and T written in 2-slice layout: [slice][node][64] fp16 (128-B rows).
__global__ __launch_bounds__(256) void gemm_mfma(const __half* __restrict__ H,
                                                 const float* __restrict__ W,
                                                 const int* __restrict__ row_st,
                                                 __half* __restrict__ T) {
    __shared__ _Float16 Whi[64 * 128];   // 16 KB
    __shared__ _Float16 Wlo[64 * 128];   // 16 KB
    const int t = threadIdx.x;
    const int c0 = (blockIdx.x & 1) * 64;

    for (int i = t; i < 128 * 64; i += 256) {
        int k = i >> 6, c = i & 63;
        float w = W[k * HID + c0 + c];
        _Float16 hi = (_Float16)w;
        _Float16 lo = (_Float16)((w - (float)hi) * 2048.0f);
        int addr = c * 128 + (((k >> 3) ^ (c & 15)) << 3) + (k & 7);
        Whi[addr] = hi;
        Wlo[addr] = lo;
    }
    __syncthreads();

    const int wv = t >> 6;
    const int l  = t & 63;
    const int lr = l & 15;
    const int lq = l >> 4;

    for (int rep = 0; rep < 4; ++rep) {
        int strip = ((blockIdx.x >> 1) * 4 + wv) * 4 + rep;
        if (strip >= N_NODES / 16) continue;
        int n0 = strip * 16;

        f32x4_t acc[4], acl[4];
#pragma unroll
        for (int ct = 0; ct < 4; ++ct) { acc[ct] = (f32x4_t){0,0,0,0}; acl[ct] = (f32x4_t){0,0,0,0}; }

#pragma unroll
        for (int kc = 0; kc < 4; ++kc) {
            // feature f = kc*32 + lq*8 + j -> slice = kc>>1, within-slice = (kc&1)*32 + lq*8
            half8_t a = *(const half8_t*)(H + ((size_t)(kc >> 1) * N_NODES + n0 + lr) * 64
                                            + (kc & 1) * 32 + lq * 8);
#pragma unroll
            for (int j = 0; j < 8; ++j) a[j] = a[j] > (_Float16)0 ? a[j] : (_Float16)0;
            int g = kc * 4 + lq;
#pragma unroll
            for (int ct = 0; ct < 4; ++ct) {
                int c = ct * 16 + lr;
                int addr = c * 128 + ((g ^ lr) << 3);
                half8_t bh = *(const half8_t*)&Whi[addr];
                half8_t bl = *(const half8_t*)&Wlo[addr];
                acc[ct] = __builtin_amdgcn_mfma_f32_16x16x32_f16(a, bh, acc[ct], 0, 0, 0);
                acl[ct] = __builtin_amdgcn_mfma_f32_16x16x32_f16(a, bl, acl[ct], 0, 0, 0);
            }
        }

        int r0 = n0 + lq * 4;
#pragma unroll
        for (int r = 0; r < 4; ++r) {
            int row = r0 + r;
            float d = rsqrtf((float)(row_st[row + 1] - row_st[row] + 1));
#pragma unroll
            for (int ct = 0; ct < 4; ++ct) {
                float v = (acc[ct][r] + acl[ct][r] * 4.8828125e-4f) * d;
                int c = c0 + ct * 16 + lr;
                T[((size_t)(c >> 6) * N_NODES + row) * 64 + (c & 63)] = __float2half(v);
            }
        }
    }
}

// ---------------- XCD-pinned half-gather: 2 slices x 64 features (128-B rows) ----------------
// blockIdx%8 -> XCD (round-robin dispatch); 4 XCDs per slice => per-XCD random working
// set = one 12.8 MB half-table (distinct ~12.5 MB vs 22 MB unsliced). Rows are full
// 128-B lines (16 lanes x 8 B) so every miss is fully used. csr reads are PLAIN
// cached loads (group-uniform, L1-broadcast). Only output stores are non-temporal.
__global__ __launch_bounds__(256) void gather_half(const __half* __restrict__ T,
                                                   const int* __restrict__ row_st,
                                                   const int* __restrict__ csr,
                                                   const float* __restrict__ bias,
                                                   __half* __restrict__ B) {
    int t = threadIdx.x;
    int b = blockIdx.x;
    int x = b & 7;
    int slice = x >> 2;                      // 4 XCDs per 64-feature half
    int chunk = (b >> 3) * 4 + (x & 3);      // dst chunk (16 nodes) within slice
    int n = chunk * 16 + (t >> 4);
    int l = t & 15;
    if (n >= N_NODES) return;
    int r0 = row_st[n], r1 = row_st[n + 1];
    float di = rsqrtf((float)(r1 - r0 + 1));
    const uint2* Tf = (const uint2*)T + (size_t)slice * N_NODES * 16;
    float4 acc = h4_to_f4(Tf[(size_t)n * 16 + l]);   // self term
    int r = r0;
    for (; r + 7 < r1; r += 8) {
        int s0 = csr[r],     s1 = csr[r + 1], s2 = csr[r + 2], s3 = csr[r + 3];
        int s4 = csr[r + 4], s5 = csr[r + 5], s6 = csr[r + 6], s7 = csr[r + 7];
        float4 v0 = h4_to_f4(Tf[(size_t)s0 * 16 + l]);
        float4 v1 = h4_to_f4(Tf[(size_t)s1 * 16 + l]);
        float4 v2 = h4_to_f4(Tf[(size_t)s2 * 16 + l]);
        float4 v3 = h4_to_f4(Tf[(size_t)s3 * 16 + l]);
        float4 v4 = h4_to_f4(Tf[(size_t)s4 * 16 + l]);
        float4 v5 = h4_to_f4(Tf[(size_t)s5 * 16 + l]);
        float4 v6 = h4_to_f4(Tf[(size_t)s6 * 16 + l]);
        float4 v7 = h4_to_f4(Tf[(size_t)s7 * 16 + l]);
        acc.x += ((v0.x + v1.x) + (v2.x + v3.x)) + ((v4.x + v5.x) + (v6.x + v7.x));
        acc.y += ((v0.y + v1.y) + (v2.y + v3.y)) + ((v4.y + v5.y) + (v6.y + v7.y));
        acc.z += ((v0.z + v1.z) + (v2.z + v3.z)) + ((v4.z + v5.z) + (v6.z + v7.z));
        acc.w += ((v0.w + v1.w) + (v2.w + v3.w)) + ((v4.w + v5.w) + (v6.w + v7.w));
    }
    for (; r + 3 < r1; r += 4) {
        int s0 = csr[r], s1 = csr[r + 1], s2 = csr[r + 2], s3 = csr[r + 3];
        float4 v0 = h4_to_f4(Tf[(size_t)s0 * 16 + l]);
        float4 v1 = h4_to_f4(Tf[(size_t)s1 * 16 + l]);
        float4 v2 = h4_to_f4(Tf[(size_t)s2 * 16 + l]);
        float4 v3 = h4_to_f4(Tf[(size_t)s3 * 16 + l]);
        acc.x += (v0.x + v1.x) + (v2.x + v3.x);
        acc.y += (v0.y + v1.y) + (v2.y + v3.y);
        acc.z += (v0.z + v1.z) + (v2.z + v3.z);
        acc.w += (v0.w + v1.w) + (v2.w + v3.w);
    }
    for (; r < r1; ++r) {
        float4 v = h4_to_f4(Tf[(size_t)csr[r] * 16 + l]);
        acc.x += v.x; acc.y += v.y; acc.z += v.z; acc.w += v.w;
    }
    float4 b4 = ((const float4*)bias)[slice * 16 + l];
    __half2 h0 = __floats2half2_rn(fmaf(di, acc.x, b4.x), fmaf(di, acc.y, b4.y));
    __half2 h1 = __floats2half2_rn(fmaf(di, acc.z, b4.z), fmaf(di, acc.w, b4.w));
    unsigned lo = *(unsigned*)&h0, hi = *(unsigned*)&h1;
    unsigned long long uv = ((unsigned long long)hi << 32) | lo;
    unsigned long long* dstp = (unsigned long long*)((uint2*)B + ((size_t)slice * N_NODES + n) * 16 + l);
    __builtin_nontemporal_store(uv, dstp);
}

// ---------------- pool + head in one kernel, no atomics (batch is sorted) ----------------
__global__ __launch_bounds__(256) void pool_head(const __half* __restrict__ H,
                                                 const int* __restrict__ batch,
                                                 const float* __restrict__ Wout,
                                                 const float* __restrict__ bout,
                                                 float* __restrict__ out) {
    __shared__ float4 part[8][32];
    __shared__ float p[HID];
    __shared__ int bounds[2];
    int g = blockIdx.x;
    int t = threadIdx.x;
    if (t < 2) {
        int target = g + t;
        int lo = 0, hi = N_NODES;
        while (lo < hi) {
            int mid = (lo + hi) >> 1;
            if (batch[mid] < target) lo = mid + 1; else hi = mid;
        }
        bounds[t] = lo;
    }
    __syncthreads();
    int lo = bounds[0], hi = bounds[1];
    int grp = t >> 5, l = t & 31;
    const uint2* Hf = (const uint2*)H;
    float4 acc = make_float4(0.f, 0.f, 0.f, 0.f);
    // 2-slice read: feature quad l -> slice l>>4, within-slice uint2 idx l&15
    const size_t sbase = (size_t)(l >> 4) * N_NODES;
    const int wi = l & 15;
    for (int n = lo + grp; n < hi; n += 8) {
        float4 v = h4_to_f4(Hf[(sbase + n) * 16 + wi]);
        acc.x += fmaxf(v.x, 0.f);
        acc.y += fmaxf(v.y, 0.f);
        acc.z += fmaxf(v.z, 0.f);
        acc.w += fmaxf(v.w, 0.f);
    }
    part[grp][l] = acc;
    __syncthreads();
    if (t < 32) {
        float4 s = part[0][t];
#pragma unroll
        for (int j = 1; j < 8; ++j) {
            float4 v = part[j][t];
            s.x += v.x; s.y += v.y; s.z += v.z; s.w += v.w;
        }
        float inv = 1.0f / fmaxf((float)(hi - lo), 1.0f);
        p[t * 4 + 0] = s.x * inv;
        p[t * 4 + 1] = s.y * inv;
        p[t * 4 + 2] = s.z * inv;
        p[t * 4 + 3] = s.w * inv;
    }
    __syncthreads();
    if (t < OUT_F) {
        float acc2 = 0.f;
#pragma unroll 8
        for (int k = 0; k < HID; ++k)
            acc2 = fmaf(p[k], Wout[k * OUT_F + t], acc2);
        out[g * OUT_F + t] = acc2 + bout[t];
    }
}

extern "C" void kernel_launch(void* const* d_in, const int* in_sizes, int n_in,
                              void* d_out, int out_size, void* d_ws, size_t ws_size,
                              hipStream_t stream) {
    const float* x     = (const float*)d_in[0];
    const int*   ei    = (const int*)d_in[1];
    const int*   batch = (const int*)d_in[2];
    const float* W1    = (const float*)d_in[3];
    const float* b1    = (const float*)d_in[4];
    const float* W2    = (const float*)d_in[5];
    const float* b2    = (const float*)d_in[6];
    const float* W3    = (const float*)d_in[7];
    const float* b3    = (const float*)d_in[8];
    const float* Wout  = (const float*)d_in[9];
    const float* bout  = (const float*)d_in[10];
    float* out = (float*)d_out;

    const int* src = ei;
    const int* dst = ei + N_EDGES;

    // workspace (within proven footprint)
    float* A      = (float*)d_ws;                        // 12.8M floats
    float* Breg   = A + (size_t)N_NODES * HID;           // 12.8M floats
    int*   row_st = (int*)(Breg + (size_t)N_NODES * HID);// 100001 ints
    int*   cur512 = row_st + N_NODES + 1;                // 512
    int*   csr    = cur512 + BUCKETS;                    // 1.6M ints

    int*    bpairs = (int*)A;                              // 512*3500*4 = 7.168 MB overlay
    __half* Xs     = (__half*)((char*)A + 7168000);        // 6.4 MB, after bpairs
    __half* T      = (__half*)A;                           // 25.6 MB msg table (after layer1)
    __half* H      = (__half*)Breg;                        // 25.6 MB activation table

    // 1. zero bucket cursors + CSR build
    hipMemsetAsync(cur512, 0, BUCKETS * sizeof(int), stream);
    partition<<<(N_EDGES + EPB - 1) / EPB, 512, 0, stream>>>(src, dst, bpairs, cur512);
    csr_build<<<BUCKETS, 512, 0, stream>>>(bpairs, cur512, row_st, csr, x, Xs);

    // 2. layer 1: fused gather(F_IN)+GEMM (2-slice H)
    layer1<<<N_NODES / 16, 256, 0, stream>>>(Xs, row_st, csr, W1, b1, H);

    // 3. layers 2/3: 2-slice tables, XCD-pinned half-gather
    // grid: 1563*8 = 12504 blocks; chunks 0..6251 (>=6250 guarded)
    gemm_mfma<<<782, 256, 0, stream>>>(H, W2, row_st, T);
    gather_half<<<12504, 256, 0, stream>>>(T, row_st, csr, b2, H);
    gemm_mfma<<<782, 256, 0, stream>>>(H, W3, row_st, T);
    gather_half<<<12504, 256, 0, stream>>>(T, row_st, csr, b3, H);

    // 4. pool + head, no atomics
    pool_head<<<N_GRAPHS, 256, 0, stream>>>(H, batch, Wout, bout, out);
}

// Round 3
// 343.349 us; speedup vs baseline: 1.2285x; 1.0562x over previous
//
#include <hip/hip_runtime.h>
#include <hip/hip_fp16.h>

#define N_NODES 100000
#define N_EDGES 1600000
#define N_GRAPHS 512
#define F_IN 20
#define HID 128
#define OUT_F 64

#define BUCKETS 512
#define SPAN 196        // ceil(N_NODES / BUCKETS)
#define BCAP 3500       // per-bucket capacity (mean 3125, +6.7 sigma)
#define EPB 4096        // edges per partition block (512 threads x 8)

typedef _Float16 half8_t __attribute__((ext_vector_type(8)));
typedef float f32x4_t __attribute__((ext_vector_type(4)));
typedef unsigned int uv4 __attribute__((ext_vector_type(4)));

__device__ inline float4 h4_to_f4(uint2 u) {
    __half2 h0 = *(__half2*)&u.x;
    __half2 h1 = *(__half2*)&u.y;
    float2 f0 = __half22float2(h0);
    float2 f1 = __half22float2(h1);
    return make_float4(f0.x, f0.y, f1.x, f1.y);
}

__device__ inline float4 f4_from(unsigned a, unsigned b) {
    __half2 h0 = *(__half2*)&a;
    __half2 h1 = *(__half2*)&b;
    float2 f0 = __half22float2(h0);
    float2 f1 = __half22float2(h1);
    return make_float4(f0.x, f0.y, f1.x, f1.y);
}

// ---------------- partition edges into 512 dst-range buckets (512 thr) ----------------
__global__ __launch_bounds__(512) void partition(const int* __restrict__ src,
                                                 const int* __restrict__ dst,
                                                 int* __restrict__ bpairs,
                                                 int* cur512) {
    __shared__ int lcnt[8][BUCKETS];   // 16 KB
    __shared__ int woff[8][BUCKETS];   // 16 KB
    int t = threadIdx.x;
    int wv = t >> 6;
    for (int i = t; i < 8 * BUCKETS; i += 512) ((int*)lcnt)[i] = 0;
    __syncthreads();
    int base = blockIdx.x * EPB;
    int myb[8], myp[8], myr[8];
#pragma unroll
    for (int i = 0; i < 8; ++i) {
        int e = base + i * 512 + t;
        int b = -1, p = 0, rk = 0;
        if (e < N_EDGES) {
            int s = src[e], d = dst[e];
            b = d / SPAN;
            p = (s << 9) | (d - b * SPAN);
            rk = atomicAdd(&lcnt[wv][b], 1);
        }
        myb[i] = b; myp[i] = p; myr[i] = rk;
    }
    __syncthreads();
    {
        int c[8], tot = 0;
#pragma unroll
        for (int w = 0; w < 8; ++w) { c[w] = lcnt[w][t]; tot += c[w]; }
        int gb = atomicAdd(&cur512[t], tot);
#pragma unroll
        for (int w = 0; w < 8; ++w) { woff[w][t] = gb; gb += c[w]; }
    }
    __syncthreads();
#pragma unroll
    for (int i = 0; i < 8; ++i) {
        int b = myb[i];
        if (b >= 0) {
            int p = woff[wv][b] + myr[i];
            if (p < BCAP) bpairs[(size_t)b * BCAP + p] = myp[i];
        }
    }
}

// ---------------- per-bucket CSR build, 512 thr (fused bbase scan + scale_x) ----------------
__global__ __launch_bounds__(512) void csr_build(const int* __restrict__ bpairs,
                                                 const int* __restrict__ cur512,
                                                 int* __restrict__ row_st,
                                                 int* __restrict__ csr,
                                                 const float* __restrict__ x,
                                                 __half* __restrict__ Xs) {
    __shared__ int ocnt[SPAN];
    __shared__ int sc[512];
    __shared__ int cur[SPAN];
    __shared__ int sbase;
    int b = blockIdx.x, t = threadIdx.x;

    // bucket base: exclusive scan of all 512 bucket counts
    int myc = cur512[t];
    sc[t] = myc;
    __syncthreads();
    for (int o = 1; o < BUCKETS; o <<= 1) {
        int v = (t >= o) ? sc[t - o] : 0;
        __syncthreads();
        sc[t] += v;
        __syncthreads();
    }
    if (t == b) sbase = sc[t] - myc;
    if (b == BUCKETS - 1 && t == 0) row_st[N_NODES] = N_EDGES;

    int n0 = b * SPAN;
    int span = N_NODES - n0; if (span > SPAN) span = SPAN;
    if (span < 0) span = 0;
    if (t < SPAN) ocnt[t] = 0;
    __syncthreads();

    int n = cur512[b];
    if (n > BCAP) n = BCAP;
    const int* p = bpairs + (size_t)b * BCAP;
    for (int i = t; i < n; i += 512) atomicAdd(&ocnt[p[i] & 511], 1);
    __syncthreads();
    sc[t] = (t < span) ? ocnt[t] : 0;
    __syncthreads();
    for (int o = 1; o < 512; o <<= 1) {
        int v = (t >= o) ? sc[t - o] : 0;
        __syncthreads();
        sc[t] += v;
        __syncthreads();
    }
    int base = sbase;
    if (t < span) {
        int start = sc[t] - ocnt[t];
        row_st[n0 + t] = base + start;
        cur[t] = start;
    }
    __syncthreads();
    for (int i = t; i < n; i += 512) {
        int e = p[i];
        int lp = atomicAdd(&cur[e & 511], 1);
        csr[base + lp] = e >> 9;
    }
    // fused scale_x for this bucket's nodes
    for (int i = t; i < span * 32; i += 512) {
        int nl = i >> 5, f = i & 31;
        float v = (f < F_IN) ? x[(size_t)(n0 + nl) * F_IN + f] : 0.f;
        float di = rsqrtf((float)(ocnt[nl] + 1));
        Xs[(size_t)(n0 + nl) * 32 + f] = __float2half(di * v);
    }
}

// ---------------- layer 1 fused: deep-pipelined gather(F_IN) + GEMM -> H fp16 ----------------
// 64 nodes/block. Gather: 4-lane groups, one 64-B Xs row per dwordx4 instr, 8-deep
// unroll (vs depth-2 before -> was latency-stalled). GEMM: interleaved columns
// c = (t&3)*4 + 16j (bank-conflict-free Wlds reads; 32-float spacing would 4-way alias).
__global__ __launch_bounds__(256) void layer1(const __half* __restrict__ Xs,
                                              const int* __restrict__ row_st,
                                              const int* __restrict__ csr,
                                              const float* __restrict__ W,
                                              const float* __restrict__ bias,
                                              __half* __restrict__ H) {
    __shared__ float Wlds[F_IN * HID];   // 10 KB
    __shared__ float Alds[64][F_IN];     // 5 KB
    const int t = threadIdx.x;
    const int node0 = blockIdx.x * 64;

    for (int i = t; i < F_IN * HID; i += 256) Wlds[i] = W[i];

    const int grp = t >> 2;          // 0..63 -> local node
    const int l   = t & 3;           // uint4 (8 halfs) within 64-B row
    const int n   = node0 + grp;
    if (n < N_NODES) {
        int r0 = row_st[n], r1 = row_st[n + 1];
        const uv4* X4 = (const uv4*)Xs;
        uv4 u = X4[(size_t)n * 4 + l];
        float4 accL = f4_from(u[0], u[1]);   // self term (Xs pre-scaled src-side)
        float4 accH = f4_from(u[2], u[3]);
        int r = r0;
        for (; r + 7 < r1; r += 8) {
            int s0 = csr[r],     s1 = csr[r + 1], s2 = csr[r + 2], s3 = csr[r + 3];
            int s4 = csr[r + 4], s5 = csr[r + 5], s6 = csr[r + 6], s7 = csr[r + 7];
            uv4 vv0 = X4[(size_t)s0 * 4 + l];
            uv4 vv1 = X4[(size_t)s1 * 4 + l];
            uv4 vv2 = X4[(size_t)s2 * 4 + l];
            uv4 vv3 = X4[(size_t)s3 * 4 + l];
            uv4 vv4 = X4[(size_t)s4 * 4 + l];
            uv4 vv5 = X4[(size_t)s5 * 4 + l];
            uv4 vv6 = X4[(size_t)s6 * 4 + l];
            uv4 vv7 = X4[(size_t)s7 * 4 + l];
            uv4 vv[8] = {vv0, vv1, vv2, vv3, vv4, vv5, vv6, vv7};
#pragma unroll
            for (int j = 0; j < 8; ++j) {
                float4 aL = f4_from(vv[j][0], vv[j][1]);
                float4 aH = f4_from(vv[j][2], vv[j][3]);
                accL.x += aL.x; accL.y += aL.y; accL.z += aL.z; accL.w += aL.w;
                accH.x += aH.x; accH.y += aH.y; accH.z += aH.z; accH.w += aH.w;
            }
        }
        for (; r < r1; ++r) {
            uv4 v = X4[(size_t)csr[r] * 4 + l];
            float4 aL = f4_from(v[0], v[1]);
            float4 aH = f4_from(v[2], v[3]);
            accL.x += aL.x; accL.y += aL.y; accL.z += aL.z; accL.w += aL.w;
            accH.x += aH.x; accH.y += aH.y; accH.z += aH.z; accH.w += aH.w;
        }
        float di = rsqrtf((float)(r1 - r0 + 1));
        // lane l owns features l*8 .. l*8+7; only f < 20 are real
        if (l < 2) {
            int f0 = l * 8;
            Alds[grp][f0 + 0] = di * accL.x;
            Alds[grp][f0 + 1] = di * accL.y;
            Alds[grp][f0 + 2] = di * accL.z;
            Alds[grp][f0 + 3] = di * accL.w;
            Alds[grp][f0 + 4] = di * accH.x;
            Alds[grp][f0 + 5] = di * accH.y;
            Alds[grp][f0 + 6] = di * accH.z;
            Alds[grp][f0 + 7] = di * accH.w;
        } else if (l == 2) {
            Alds[grp][16] = di * accL.x;
            Alds[grp][17] = di * accL.y;
            Alds[grp][18] = di * accL.z;
            Alds[grp][19] = di * accL.w;
        }
    }
    __syncthreads();

    // GEMM phase: thread t -> node (t>>2), cols c(j) = (t&3)*4 + 16*j, j=0..7
    const int nl = t >> 2;
    const int cb = (t & 3) * 4;
    float4 acc[8];
#pragma unroll
    for (int j = 0; j < 8; ++j) acc[j] = *(const float4*)&bias[cb + 16 * j];
#pragma unroll
    for (int k = 0; k < F_IN; ++k) {
        float a = Alds[nl][k];
        const float* Wr = &Wlds[k * HID + cb];
#pragma unroll
        for (int j = 0; j < 8; ++j) {
            float4 w = *(const float4*)&Wr[16 * j];
            acc[j].x = fmaf(a, w.x, acc[j].x);
            acc[j].y = fmaf(a, w.y, acc[j].y);
            acc[j].z = fmaf(a, w.z, acc[j].z);
            acc[j].w = fmaf(a, w.w, acc[j].w);
        }
    }
    if (node0 + nl < N_NODES) {
#pragma unroll
        for (int j = 0; j < 8; ++j) {
            int c = cb + 16 * j;
            int slice = c >> 6;
            int wi = (t & 3) + 4 * (j & 3);   // uint2 index within 64-feature slice row
            __half2 h0 = __floats2half2_rn(acc[j].x, acc[j].y);
            __half2 h1 = __floats2half2_rn(acc[j].z, acc[j].w);
            uint2 u; u.x = *(unsigned*)&h0; u.y = *(unsigned*)&h1;
            ((uint2*)H)[((size_t)slice * N_NODES + node0 + nl) * 16 + wi] = u;
        }
    }
}

// ---------------- layers-2/3 GEMM via MFMA (column-split: 64 cols/block) ----------------
// H read and T written in 2-slice layout: [slice][node][64] fp16 (128-B rows).
__global__ __launch_bounds__(256) void gemm_mfma(const __half* __restrict__ H,
                                                 const float* __restrict__ W,
                                                 const int* __restrict__ row_st,
                                                 __half* __restrict__ T) {
    __shared__ _Float16 Whi[64 * 128];   // 16 KB
    __shared__ _Float16 Wlo[64 * 128];   // 16 KB
    const int t = threadIdx.x;
    const int c0 = (blockIdx.x & 1) * 64;

    for (int i = t; i < 128 * 64; i += 256) {
        int k = i >> 6, c = i & 63;
        float w = W[k * HID + c0 + c];
        _Float16 hi = (_Float16)w;
        _Float16 lo = (_Float16)((w - (float)hi) * 2048.0f);
        int addr = c * 128 + (((k >> 3) ^ (c & 15)) << 3) + (k & 7);
        Whi[addr] = hi;
        Wlo[addr] = lo;
    }
    __syncthreads();

    const int wv = t >> 6;
    const int l  = t & 63;
    const int lr = l & 15;
    const int lq = l >> 4;

    for (int rep = 0; rep < 4; ++rep) {
        int strip = ((blockIdx.x >> 1) * 4 + wv) * 4 + rep;
        if (strip >= N_NODES / 16) continue;
        int n0 = strip * 16;

        f32x4_t acc[4], acl[4];
#pragma unroll
        for (int ct = 0; ct < 4; ++ct) { acc[ct] = (f32x4_t){0,0,0,0}; acl[ct] = (f32x4_t){0,0,0,0}; }

#pragma unroll
        for (int kc = 0; kc < 4; ++kc) {
            // feature f = kc*32 + lq*8 + j -> slice = kc>>1, within-slice = (kc&1)*32 + lq*8
            half8_t a = *(const half8_t*)(H + ((size_t)(kc >> 1) * N_NODES + n0 + lr) * 64
                                            + (kc & 1) * 32 + lq * 8);
#pragma unroll
            for (int j = 0; j < 8; ++j) a[j] = a[j] > (_Float16)0 ? a[j] : (_Float16)0;
            int g = kc * 4 + lq;
#pragma unroll
            for (int ct = 0; ct < 4; ++ct) {
                int c = ct * 16 + lr;
                int addr = c * 128 + ((g ^ lr) << 3);
                half8_t bh = *(const half8_t*)&Whi[addr];
                half8_t bl = *(const half8_t*)&Wlo[addr];
                acc[ct] = __builtin_amdgcn_mfma_f32_16x16x32_f16(a, bh, acc[ct], 0, 0, 0);
                acl[ct] = __builtin_amdgcn_mfma_f32_16x16x32_f16(a, bl, acl[ct], 0, 0, 0);
            }
        }

        int r0 = n0 + lq * 4;
#pragma unroll
        for (int r = 0; r < 4; ++r) {
            int row = r0 + r;
            float d = rsqrtf((float)(row_st[row + 1] - row_st[row] + 1));
#pragma unroll
            for (int ct = 0; ct < 4; ++ct) {
                float v = (acc[ct][r] + acl[ct][r] * 4.8828125e-4f) * d;
                int c = c0 + ct * 16 + lr;
                T[((size_t)(c >> 6) * N_NODES + row) * 64 + (c & 63)] = __float2half(v);
            }
        }
    }
}

// ---------------- XCD-pinned half-gather: 2 slices x 64 features (128-B rows) ----------------
// blockIdx%8 -> XCD; 4 XCDs per slice. 8-lane groups x dwordx4: one full 128-B row
// per VMEM instr (8 rows per wave-instr, 8-deep unroll -> 64 rows in flight per wave).
// Request count stays 3.4M (the measured floor); this halves VMEM instr count and
// doubles per-wave MSHR feed. csr loads plain (broadcast). Output stores non-temporal.
__global__ __launch_bounds__(256) void gather_half(const __half* __restrict__ T,
                                                   const int* __restrict__ row_st,
                                                   const int* __restrict__ csr,
                                                   const float* __restrict__ bias,
                                                   __half* __restrict__ B) {
    int t = threadIdx.x;
    int b = blockIdx.x;
    int x = b & 7;
    int slice = x >> 2;                      // 4 XCDs per 64-feature half
    int chunk = (b >> 3) * 4 + (x & 3);      // dst chunk (32 nodes) within slice
    int n = chunk * 32 + (t >> 3);
    int l = t & 7;                           // uint4 (8 halfs) within 128-B row
    if (n >= N_NODES) return;
    int r0 = row_st[n], r1 = row_st[n + 1];
    float di = rsqrtf((float)(r1 - r0 + 1));
    const uv4* Tf = (const uv4*)T + (size_t)slice * N_NODES * 8;
    uv4 u = Tf[(size_t)n * 8 + l];
    float4 accL = f4_from(u[0], u[1]);       // self term
    float4 accH = f4_from(u[2], u[3]);
    int r = r0;
    for (; r + 7 < r1; r += 8) {
        int s0 = csr[r],     s1 = csr[r + 1], s2 = csr[r + 2], s3 = csr[r + 3];
        int s4 = csr[r + 4], s5 = csr[r + 5], s6 = csr[r + 6], s7 = csr[r + 7];
        uv4 vv0 = Tf[(size_t)s0 * 8 + l];
        uv4 vv1 = Tf[(size_t)s1 * 8 + l];
        uv4 vv2 = Tf[(size_t)s2 * 8 + l];
        uv4 vv3 = Tf[(size_t)s3 * 8 + l];
        uv4 vv4 = Tf[(size_t)s4 * 8 + l];
        uv4 vv5 = Tf[(size_t)s5 * 8 + l];
        uv4 vv6 = Tf[(size_t)s6 * 8 + l];
        uv4 vv7 = Tf[(size_t)s7 * 8 + l];
        uv4 vv[8] = {vv0, vv1, vv2, vv3, vv4, vv5, vv6, vv7};
#pragma unroll
        for (int j = 0; j < 8; ++j) {
            float4 aL = f4_from(vv[j][0], vv[j][1]);
            float4 aH = f4_from(vv[j][2], vv[j][3]);
            accL.x += aL.x; accL.y += aL.y; accL.z += aL.z; accL.w += aL.w;
            accH.x += aH.x; accH.y += aH.y; accH.z += aH.z; accH.w += aH.w;
        }
    }
    for (; r + 3 < r1; r += 4) {
        int s0 = csr[r], s1 = csr[r + 1], s2 = csr[r + 2], s3 = csr[r + 3];
        uv4 vv0 = Tf[(size_t)s0 * 8 + l];
        uv4 vv1 = Tf[(size_t)s1 * 8 + l];
        uv4 vv2 = Tf[(size_t)s2 * 8 + l];
        uv4 vv3 = Tf[(size_t)s3 * 8 + l];
        uv4 vv[4] = {vv0, vv1, vv2, vv3};
#pragma unroll
        for (int j = 0; j < 4; ++j) {
            float4 aL = f4_from(vv[j][0], vv[j][1]);
            float4 aH = f4_from(vv[j][2], vv[j][3]);
            accL.x += aL.x; accL.y += aL.y; accL.z += aL.z; accL.w += aL.w;
            accH.x += aH.x; accH.y += aH.y; accH.z += aH.z; accH.w += aH.w;
        }
    }
    for (; r < r1; ++r) {
        uv4 v = Tf[(size_t)csr[r] * 8 + l];
        float4 aL = f4_from(v[0], v[1]);
        float4 aH = f4_from(v[2], v[3]);
        accL.x += aL.x; accL.y += aL.y; accL.z += aL.z; accL.w += aL.w;
        accH.x += aH.x; accH.y += aH.y; accH.z += aH.z; accH.w += aH.w;
    }
    const float4* bb = (const float4*)bias + slice * 16 + l * 2;
    float4 b0 = bb[0], b1 = bb[1];
    __half2 h0 = __floats2half2_rn(fmaf(di, accL.x, b0.x), fmaf(di, accL.y, b0.y));
    __half2 h1 = __floats2half2_rn(fmaf(di, accL.z, b0.z), fmaf(di, accL.w, b0.w));
    __half2 h2 = __floats2half2_rn(fmaf(di, accH.x, b1.x), fmaf(di, accH.y, b1.y));
    __half2 h3 = __floats2half2_rn(fmaf(di, accH.z, b1.z), fmaf(di, accH.w, b1.w));
    uv4 o;
    o[0] = *(unsigned*)&h0; o[1] = *(unsigned*)&h1;
    o[2] = *(unsigned*)&h2; o[3] = *(unsigned*)&h3;
    uv4* dstp = (uv4*)B + ((size_t)slice * N_NODES + n) * 8 + l;
    __builtin_nontemporal_store(o, dstp);
}

// ---------------- pool + head in one kernel, no atomics (batch is sorted) ----------------
__global__ __launch_bounds__(256) void pool_head(const __half* __restrict__ H,
                                                 const int* __restrict__ batch,
                                                 const float* __restrict__ Wout,
                                                 const float* __restrict__ bout,
                                                 float* __restrict__ out) {
    __shared__ float4 part[8][32];
    __shared__ float p[HID];
    __shared__ int bounds[2];
    int g = blockIdx.x;
    int t = threadIdx.x;
    if (t < 2) {
        int target = g + t;
        int lo = 0, hi = N_NODES;
        while (lo < hi) {
            int mid = (lo + hi) >> 1;
            if (batch[mid] < target) lo = mid + 1; else hi = mid;
        }
        bounds[t] = lo;
    }
    __syncthreads();
    int lo = bounds[0], hi = bounds[1];
    int grp = t >> 5, l = t & 31;
    const uint2* Hf = (const uint2*)H;
    float4 acc = make_float4(0.f, 0.f, 0.f, 0.f);
    // 2-slice read: feature quad l -> slice l>>4, within-slice uint2 idx l&15
    const size_t sbase = (size_t)(l >> 4) * N_NODES;
    const int wi = l & 15;
    for (int n = lo + grp; n < hi; n += 8) {
        float4 v = h4_to_f4(Hf[(sbase + n) * 16 + wi]);
        acc.x += fmaxf(v.x, 0.f);
        acc.y += fmaxf(v.y, 0.f);
        acc.z += fmaxf(v.z, 0.f);
        acc.w += fmaxf(v.w, 0.f);
    }
    part[grp][l] = acc;
    __syncthreads();
    if (t < 32) {
        float4 s = part[0][t];
#pragma unroll
        for (int j = 1; j < 8; ++j) {
            float4 v = part[j][t];
            s.x += v.x; s.y += v.y; s.z += v.z; s.w += v.w;
        }
        float inv = 1.0f / fmaxf((float)(hi - lo), 1.0f);
        p[t * 4 + 0] = s.x * inv;
        p[t * 4 + 1] = s.y * inv;
        p[t * 4 + 2] = s.z * inv;
        p[t * 4 + 3] = s.w * inv;
    }
    __syncthreads();
    if (t < OUT_F) {
        float acc2 = 0.f;
#pragma unroll 8
        for (int k = 0; k < HID; ++k)
            acc2 = fmaf(p[k], Wout[k * OUT_F + t], acc2);
        out[g * OUT_F + t] = acc2 + bout[t];
    }
}

extern "C" void kernel_launch(void* const* d_in, const int* in_sizes, int n_in,
                              void* d_out, int out_size, void* d_ws, size_t ws_size,
                              hipStream_t stream) {
    const float* x     = (const float*)d_in[0];
    const int*   ei    = (const int*)d_in[1];
    const int*   batch = (const int*)d_in[2];
    const float* W1    = (const float*)d_in[3];
    const float* b1    = (const float*)d_in[4];
    const float* W2    = (const float*)d_in[5];
    const float* b2    = (const float*)d_in[6];
    const float* W3    = (const float*)d_in[7];
    const float* b3    = (const float*)d_in[8];
    const float* Wout  = (const float*)d_in[9];
    const float* bout  = (const float*)d_in[10];
    float* out = (float*)d_out;

    const int* src = ei;
    const int* dst = ei + N_EDGES;

    // workspace (within proven footprint)
    float* A      = (float*)d_ws;                        // 12.8M floats
    float* Breg   = A + (size_t)N_NODES * HID;           // 12.8M floats
    int*   row_st = (int*)(Breg + (size_t)N_NODES * HID);// 100001 ints
    int*   cur512 = row_st + N_NODES + 1;                // 512
    int*   csr    = cur512 + BUCKETS;                    // 1.6M ints

    int*    bpairs = (int*)A;                              // 512*3500*4 = 7.168 MB overlay
    __half* Xs     = (__half*)((char*)A + 7168000);        // 6.4 MB, after bpairs
    __half* T      = (__half*)A;                           // 25.6 MB msg table (after layer1)
    __half* H      = (__half*)Breg;                        // 25.6 MB activation table

    // 1. zero bucket cursors + CSR build
    hipMemsetAsync(cur512, 0, BUCKETS * sizeof(int), stream);
    partition<<<(N_EDGES + EPB - 1) / EPB, 512, 0, stream>>>(src, dst, bpairs, cur512);
    csr_build<<<BUCKETS, 512, 0, stream>>>(bpairs, cur512, row_st, csr, x, Xs);

    // 2. layer 1: deep-pipelined gather(F_IN)+GEMM (2-slice H), 64 nodes/block
    layer1<<<(N_NODES + 63) / 64, 256, 0, stream>>>(Xs, row_st, csr, W1, b1, H);

    // 3. layers 2/3: 2-slice tables, XCD-pinned half-gather (32 nodes/block)
    // grid: 782*8 = 6256 blocks; chunks 0..3127 (>=3125 guarded)
    gemm_mfma<<<782, 256, 0, stream>>>(H, W2, row_st, T);
    gather_half<<<6256, 256, 0, stream>>>(T, row_st, csr, b2, H);
    gemm_mfma<<<782, 256, 0, stream>>>(H, W3, row_st, T);
    gather_half<<<6256, 256, 0, stream>>>(T, row_st, csr, b3, H);

    // 4. pool + head, no atomics
    pool_head<<<N_GRAPHS, 256, 0, stream>>>(H, batch, Wout, bout, out);
}